// Round 4
// baseline (1320.845 us; speedup 1.0000x reference)
//
#include <hip/hip_runtime.h>

#define B_DIM   2048
#define IN_DIM  4096
#define OUT_DIM 4096
#define FAN     64

// R4: double-buffered gather.
//  Phase 1 (unchanged): pack fp32 input -> bf16 cell layout in d_ws.
//    Cell (t,c) = 16 B: dword k = bf16(rows 2k,2k+1) of tile t (8 rows), column c.
//  Phase 2: 512-thread blocks, 1 block/CU (grid 32 bsegs x 8 oblocks = 256),
//    2 x 64 KB LDS buffers (128 KB dynamic LDS). Per tile: issue DMA for tile
//    t+1 into the spare buffer, compute on current, ONE barrier (drains a DMA
//    that has had the whole compute phase to finish). Buffer select is folded
//    into the 64 gather-address registers via XOR 0x10000 between tiles.
//    Inner loop: ds_read_b128 (8 rows) -> 4x v_pk_fma_f32 via float2.

typedef float v2f __attribute__((ext_vector_type(2)));

__device__ __forceinline__ unsigned bf16_rne(float f) {
    unsigned u = __float_as_uint(f);
    return (u + 0x7fffu + ((u >> 16) & 1u)) >> 16;   // round-to-nearest-even bf16
}

// ---------------- Phase 1: pack fp32 -> bf16 cells ----------------
__global__ __launch_bounds__(256) void pack_kernel(
    const float* __restrict__ input, uint4* __restrict__ wsp)
{
    const int idx = blockIdx.x * 256 + threadIdx.x;   // [0, 524288): 2 cells each
    const int t   = idx >> 11;                        // tile [0,256)
    const int c0  = (idx & 2047) << 1;                // column pair [0,4096)

    const float* p = input + (size_t)t * 8 * IN_DIM + c0;
    const float2 r0 = *reinterpret_cast<const float2*>(p + 0 * IN_DIM);
    const float2 r1 = *reinterpret_cast<const float2*>(p + 1 * IN_DIM);
    const float2 r2 = *reinterpret_cast<const float2*>(p + 2 * IN_DIM);
    const float2 r3 = *reinterpret_cast<const float2*>(p + 3 * IN_DIM);
    const float2 r4 = *reinterpret_cast<const float2*>(p + 4 * IN_DIM);
    const float2 r5 = *reinterpret_cast<const float2*>(p + 5 * IN_DIM);
    const float2 r6 = *reinterpret_cast<const float2*>(p + 6 * IN_DIM);
    const float2 r7 = *reinterpret_cast<const float2*>(p + 7 * IN_DIM);

    uint4 a, b;
    a.x = bf16_rne(r0.x) | (bf16_rne(r1.x) << 16);
    a.y = bf16_rne(r2.x) | (bf16_rne(r3.x) << 16);
    a.z = bf16_rne(r4.x) | (bf16_rne(r5.x) << 16);
    a.w = bf16_rne(r6.x) | (bf16_rne(r7.x) << 16);
    b.x = bf16_rne(r0.y) | (bf16_rne(r1.y) << 16);
    b.y = bf16_rne(r2.y) | (bf16_rne(r3.y) << 16);
    b.z = bf16_rne(r4.y) | (bf16_rne(r5.y) << 16);
    b.w = bf16_rne(r6.y) | (bf16_rne(r7.y) << 16);

    uint4* q = wsp + (size_t)t * IN_DIM + c0;
    q[0] = a;
    q[1] = b;
}

// ---------------- Phase 2: double-buffered gather + accumulate ----------------
__global__ __launch_bounds__(512, 2) void condensed_kernel(
    const uint4* __restrict__ wsp,
    const float* __restrict__ weight,
    const float* __restrict__ bias,
    const int*   __restrict__ mask,
    float*       __restrict__ out)
{
    extern __shared__ __align__(16) uint4 lds[];      // 2 x 4096 cells = 128 KB

    const int tid   = threadIdx.x;                    // [0,512)
    const int o     = blockIdx.y * 512 + tid;
    const int bseg  = blockIdx.x * 64;                // 64 batch rows per block
    const int tbase = bseg >> 3;                      // first tile index

    // ---- idx -> LDS byte addresses (buf0) + weights, in registers ----
    unsigned addrs[FAN];
    float    wv[FAN];
    {
        const int4*   mv = reinterpret_cast<const int4*>(mask)     + o * (FAN / 4);
        const float4* wp = reinterpret_cast<const float4*>(weight) + o * (FAN / 4);
        #pragma unroll
        for (int j = 0; j < FAN / 4; ++j) {
            int4   m4 = mv[j];
            float4 w4 = wp[j];
            addrs[4*j+0] = (unsigned)m4.x << 4;
            addrs[4*j+1] = (unsigned)m4.y << 4;
            addrs[4*j+2] = (unsigned)m4.z << 4;
            addrs[4*j+3] = (unsigned)m4.w << 4;
            wv[4*j+0] = w4.x;
            wv[4*j+1] = w4.y;
            wv[4*j+2] = w4.z;
            wv[4*j+3] = w4.w;
        }
    }
    const float bv = bias[o];

    // ---- prologue: DMA tile 0 -> buf0 ----
    {
        const uint4* src = wsp + (size_t)tbase * IN_DIM + tid;
        #pragma unroll
        for (int it = 0; it < 8; ++it) {
            __builtin_amdgcn_global_load_lds(
                (const __attribute__((address_space(1))) unsigned*)(src + it * 512),
                (__attribute__((address_space(3))) unsigned*)(lds + it * 512 + tid),
                16, 0, 0);
        }
    }
    __syncthreads();                                  // buf0 resident

    for (int bt = 0; bt < 8; ++bt) {
        // ---- prefetch tile bt+1 into the spare buffer (freed last barrier) ----
        if (bt < 7) {
            const uint4* src = wsp + (size_t)(tbase + bt + 1) * IN_DIM + tid;
            uint4*       dst = lds + ((bt + 1) & 1) * IN_DIM + tid;
            #pragma unroll
            for (int it = 0; it < 8; ++it) {
                __builtin_amdgcn_global_load_lds(
                    (const __attribute__((address_space(1))) unsigned*)(src + it * 512),
                    (__attribute__((address_space(3))) unsigned*)(dst + it * 512),
                    16, 0, 0);
            }
        }

        // ---- gather + accumulate on current buffer (addrs point at it) ----
        v2f a01 = {0.f, 0.f}, a23 = {0.f, 0.f}, a45 = {0.f, 0.f}, a67 = {0.f, 0.f};
        #pragma unroll
        for (int j = 0; j < FAN; ++j) {
            const uint4 g = *reinterpret_cast<const uint4*>(
                reinterpret_cast<const char*>(lds) + addrs[j]);
            const v2f w2 = {wv[j], wv[j]};
            v2f v;
            v.x = __uint_as_float(g.x << 16);
            v.y = __uint_as_float(g.x & 0xffff0000u);
            a01 = __builtin_elementwise_fma(v, w2, a01);
            v.x = __uint_as_float(g.y << 16);
            v.y = __uint_as_float(g.y & 0xffff0000u);
            a23 = __builtin_elementwise_fma(v, w2, a23);
            v.x = __uint_as_float(g.z << 16);
            v.y = __uint_as_float(g.z & 0xffff0000u);
            a45 = __builtin_elementwise_fma(v, w2, a45);
            v.x = __uint_as_float(g.w << 16);
            v.y = __uint_as_float(g.w & 0xffff0000u);
            a67 = __builtin_elementwise_fma(v, w2, a67);
        }

        // ---- flip address set to the other buffer for next tile ----
        #pragma unroll
        for (int j = 0; j < FAN; ++j) addrs[j] ^= 0x10000u;

        // ---- write 8 outputs (coalesced across 512 threads) ----
        float* op = out + (size_t)(bseg + bt * 8) * OUT_DIM + o;
        op[0 * OUT_DIM] = a01.x + bv;
        op[1 * OUT_DIM] = a01.y + bv;
        op[2 * OUT_DIM] = a23.x + bv;
        op[3 * OUT_DIM] = a23.y + bv;
        op[4 * OUT_DIM] = a45.x + bv;
        op[5 * OUT_DIM] = a45.y + bv;
        op[6 * OUT_DIM] = a67.x + bv;
        op[7 * OUT_DIM] = a67.y + bv;

        // ONE barrier: readers of current buf done (safe to overwrite next iter)
        // AND drains vmcnt -> prefetched tile bt+1 resident.
        __syncthreads();
    }
}

extern "C" void kernel_launch(void* const* d_in, const int* in_sizes, int n_in,
                              void* d_out, int out_size, void* d_ws, size_t ws_size,
                              hipStream_t stream) {
    const float* input  = (const float*)d_in[0];
    const float* weight = (const float*)d_in[1];
    const float* bias   = (const float*)d_in[2];
    const int*   mask   = (const int*)d_in[3];
    float*       out    = (float*)d_out;
    uint4*       wsp    = (uint4*)d_ws;               // needs 16 MiB

    pack_kernel<<<2048, 256, 0, stream>>>(input, wsp);

    // 128 KB dynamic LDS needs the opt-in attribute (host-side, capture-safe,
    // idempotent -> same work every call).
    hipFuncSetAttribute(reinterpret_cast<const void*>(condensed_kernel),
                        hipFuncAttributeMaxDynamicSharedMemorySize, 131072);
    dim3 grid(32, 8);    // 256 blocks = 1/CU (128 KB LDS each)
    condensed_kernel<<<grid, 512, 131072, stream>>>(wsp, weight, bias, mask, out);
}

// Round 5
// 130.449 us; speedup vs baseline: 10.1253x; 10.1253x over previous
//
#include <hip/hip_runtime.h>

#define B_DIM   2048
#define IN_DIM  4096
#define OUT_DIM 4096
#define FAN     64

// R5: half-tile software pipeline, no loop-carried address state (R4's spill bug).
//  Phase 1: pack fp32 -> bf16 4-ROW cells in d_ws. Tile t = rows 4t..4t+3,
//    cell (t,c) = 8 B at ws[(t*4096+c)*8]: dword0 = bf16 rows(0,1), dword1 = rows(2,3).
//  Phase 2: R3's grid (32 bsegs x 16 oblocks = 512 blocks, 2/CU), 256 threads,
//    64 KB static LDS = TWO 32 KB buffers. Per half-tile: DMA next half into the
//    spare buffer (global_load_lds width=16), gather current with ds_read_b64,
//    one barrier. Buffer parity = compile-time ds_read offset:32768 on the SAME
//    address registers -> zero extra VALU, addrs stay rematerializable.
//    Inner: ds_read_b64 (4 rows) -> 2x v_pk_fma_f32.

typedef float v2f __attribute__((ext_vector_type(2)));

__device__ __forceinline__ unsigned bf16_rne(float f) {
    unsigned u = __float_as_uint(f);
    return (u + 0x7fffu + ((u >> 16) & 1u)) >> 16;   // round-to-nearest-even bf16
}

// ---------------- Phase 1: pack fp32 -> bf16 4-row cells ----------------
__global__ __launch_bounds__(256) void pack_kernel(
    const float* __restrict__ input, uint4* __restrict__ wsp)
{
    const int idx = blockIdx.x * 256 + threadIdx.x;   // [0, 1048576) cell-pairs
    const int t   = idx >> 11;                        // tile [0,512)
    const int c0  = (idx & 2047) << 1;                // column pair base

    const float* p = input + (size_t)t * 4 * IN_DIM + c0;
    const float2 r0 = *reinterpret_cast<const float2*>(p + 0 * IN_DIM);
    const float2 r1 = *reinterpret_cast<const float2*>(p + 1 * IN_DIM);
    const float2 r2 = *reinterpret_cast<const float2*>(p + 2 * IN_DIM);
    const float2 r3 = *reinterpret_cast<const float2*>(p + 3 * IN_DIM);

    uint4 q;                                          // cells c0 and c0+1
    q.x = bf16_rne(r0.x) | (bf16_rne(r1.x) << 16);
    q.y = bf16_rne(r2.x) | (bf16_rne(r3.x) << 16);
    q.z = bf16_rne(r0.y) | (bf16_rne(r1.y) << 16);
    q.w = bf16_rne(r2.y) | (bf16_rne(r3.y) << 16);

    wsp[(size_t)t * 2048 + (c0 >> 1)] = q;
}

// ---------------- Phase 2: pipelined gather + accumulate ----------------
__global__ __launch_bounds__(256, 2) void condensed_kernel(
    const uint4* __restrict__ wsp,
    const float* __restrict__ weight,
    const float* __restrict__ bias,
    const int*   __restrict__ mask,
    float*       __restrict__ out)
{
    __shared__ __align__(16) uint4 lds[4096];         // 64 KB = 2 x 2048 uint4

    const int tid   = threadIdx.x;
    const int o     = blockIdx.y * 256 + tid;
    const int bseg  = blockIdx.x * 64;                // 64 batch rows per block
    const int tbase = bseg >> 2;                      // first 4-row tile (16/block)

    // ---- idx -> LDS byte addresses (cell = 8 B) + weights, in registers ----
    unsigned addrs[FAN];
    float    wv[FAN];
    {
        const int4*   mv = reinterpret_cast<const int4*>(mask)     + o * (FAN / 4);
        const float4* wp = reinterpret_cast<const float4*>(weight) + o * (FAN / 4);
        #pragma unroll
        for (int j = 0; j < FAN / 4; ++j) {
            int4   m4 = mv[j];
            float4 w4 = wp[j];
            addrs[4*j+0] = (unsigned)m4.x << 3;
            addrs[4*j+1] = (unsigned)m4.y << 3;
            addrs[4*j+2] = (unsigned)m4.z << 3;
            addrs[4*j+3] = (unsigned)m4.w << 3;
            wv[4*j+0] = w4.x;
            wv[4*j+1] = w4.y;
            wv[4*j+2] = w4.z;
            wv[4*j+3] = w4.w;
        }
    }
    const float bv = bias[o];

    // ---- prologue: DMA half-tile 0 -> buf0 ----
    {
        const uint4* src = wsp + (size_t)tbase * 2048 + tid;
        #pragma unroll
        for (int it = 0; it < 8; ++it) {
            __builtin_amdgcn_global_load_lds(
                (const __attribute__((address_space(1))) unsigned*)(src + it * 256),
                (__attribute__((address_space(3))) unsigned*)(lds + it * 256 + tid),
                16, 0, 0);
        }
    }
    __syncthreads();

    const char* ldsb = reinterpret_cast<const char*>(lds);

    for (int hp = 0; hp < 8; ++hp) {
        const int h0 = hp * 2;

        // ==== stage A: prefetch half h0+1 -> buf1, compute buf0 (offset 0) ====
        {
            const uint4* src = wsp + (size_t)(tbase + h0 + 1) * 2048 + tid;
            #pragma unroll
            for (int it = 0; it < 8; ++it) {
                __builtin_amdgcn_global_load_lds(
                    (const __attribute__((address_space(1))) unsigned*)(src + it * 256),
                    (__attribute__((address_space(3))) unsigned*)(lds + 2048 + it * 256 + tid),
                    16, 0, 0);
            }
        }
        {
            v2f a01 = {0.f, 0.f}, a23 = {0.f, 0.f};
            #pragma unroll
            for (int j = 0; j < FAN; ++j) {
                const uint2 g = *reinterpret_cast<const uint2*>(ldsb + addrs[j]);
                const v2f w2 = {wv[j], wv[j]};
                v2f v;
                v.x = __uint_as_float(g.x << 16);
                v.y = __uint_as_float(g.x & 0xffff0000u);
                a01 = __builtin_elementwise_fma(v, w2, a01);
                v.x = __uint_as_float(g.y << 16);
                v.y = __uint_as_float(g.y & 0xffff0000u);
                a23 = __builtin_elementwise_fma(v, w2, a23);
            }
            float* op = out + (size_t)(bseg + 4 * h0) * OUT_DIM + o;
            op[0 * OUT_DIM] = a01.x + bv;
            op[1 * OUT_DIM] = a01.y + bv;
            op[2 * OUT_DIM] = a23.x + bv;
            op[3 * OUT_DIM] = a23.y + bv;
        }
        __syncthreads();   // buf0 free; DMA(h0+1 -> buf1) drained

        // ==== stage B: prefetch half h0+2 -> buf0, compute buf1 (offset 32768) ====
        if (hp < 7) {
            const uint4* src = wsp + (size_t)(tbase + h0 + 2) * 2048 + tid;
            #pragma unroll
            for (int it = 0; it < 8; ++it) {
                __builtin_amdgcn_global_load_lds(
                    (const __attribute__((address_space(1))) unsigned*)(src + it * 256),
                    (__attribute__((address_space(3))) unsigned*)(lds + it * 256 + tid),
                    16, 0, 0);
            }
        }
        {
            v2f a01 = {0.f, 0.f}, a23 = {0.f, 0.f};
            #pragma unroll
            for (int j = 0; j < FAN; ++j) {
                // +32768 = buf1; compile-time constant folds into ds_read offset
                const uint2 g = *reinterpret_cast<const uint2*>(ldsb + 32768 + addrs[j]);
                const v2f w2 = {wv[j], wv[j]};
                v2f v;
                v.x = __uint_as_float(g.x << 16);
                v.y = __uint_as_float(g.x & 0xffff0000u);
                a01 = __builtin_elementwise_fma(v, w2, a01);
                v.x = __uint_as_float(g.y << 16);
                v.y = __uint_as_float(g.y & 0xffff0000u);
                a23 = __builtin_elementwise_fma(v, w2, a23);
            }
            float* op = out + (size_t)(bseg + 4 * h0 + 4) * OUT_DIM + o;
            op[0 * OUT_DIM] = a01.x + bv;
            op[1 * OUT_DIM] = a01.y + bv;
            op[2 * OUT_DIM] = a23.x + bv;
            op[3 * OUT_DIM] = a23.y + bv;
        }
        __syncthreads();   // buf1 free; DMA(h0+2 -> buf0) drained
    }
}

extern "C" void kernel_launch(void* const* d_in, const int* in_sizes, int n_in,
                              void* d_out, int out_size, void* d_ws, size_t ws_size,
                              hipStream_t stream) {
    const float* input  = (const float*)d_in[0];
    const float* weight = (const float*)d_in[1];
    const float* bias   = (const float*)d_in[2];
    const int*   mask   = (const int*)d_in[3];
    float*       out    = (float*)d_out;
    uint4*       wsp    = (uint4*)d_ws;               // needs 16 MiB

    pack_kernel<<<4096, 256, 0, stream>>>(input, wsp);
    dim3 grid(32, 16);   // 512 blocks = 2/CU (64 KB LDS each) — R3's proven grid
    condensed_kernel<<<grid, 256, 0, stream>>>(wsp, weight, bias, mask, out);
}